// Round 8
// baseline (50.232 us; speedup 1.0000x reference)
//
#include <hip/hip_runtime.h>

// LoKr via layout-chained MFMA (f16 inputs, fp32 accum), zero LDS.
// Per batch row b, with Xb = reshape(x[b], 64m x 64n):
//   PT(64n x 16r) = Xb^T @ w1b          (contract m, 16 mfma)
//   QT(16s x 16r) = w2b^T @ PT          (contract n,  4 mfma)
//   U (16r x 64k) = Q @ w2a             (contract s,  4 mfma)
//   y (64l x 64k) = (w1a^T/16) @ U      (contract r, 16 mfma)
// All with v_mfma_f32_16x16x16_f16; C-frag layout == next A/B-frag layout at
// every junction -> chain stays in registers. No LDS, no SMEM in the loop.
// R8: ROWS 4->2, grid 512->1024: 16 waves/CU (4/SIMD) == VGPR-120 cap,
// doubling latency-hiding TLP (R7 was grid-limited at 2/SIMD, pipes ~3% busy).

typedef __fp16 h2 __attribute__((ext_vector_type(2)));
typedef __fp16 h4 __attribute__((ext_vector_type(4)));
typedef float  f4 __attribute__((ext_vector_type(4)));

__device__ __forceinline__ h4 pack4(float a, float b, float c, float d) {
    h2 lo = __builtin_amdgcn_cvt_pkrtz(a, b);
    h2 hi = __builtin_amdgcn_cvt_pkrtz(c, d);
    h4 r;
    r[0] = lo[0]; r[1] = lo[1]; r[2] = hi[0]; r[3] = hi[1];
    return r;
}

#define MFMA16(a, b, c) __builtin_amdgcn_mfma_f32_16x16x16f16((a), (b), (c), 0, 0, 0)

#define ROWS 2   // rows per wave; 1024 blocks x 4 waves x 2 rows = 8192

__global__ __launch_bounds__(256) void lokr_kernel(
    const float* __restrict__ x,
    const float* __restrict__ w1_a,   // (16, 64) [r][l]
    const float* __restrict__ w1_b,   // (64, 16) [m][r]
    const float* __restrict__ w2_a,   // (16, 64) [s][k]
    const float* __restrict__ w2_b,   // (64, 16) [n][s]
    float* __restrict__ out)
{
    const int lane = threadIdx.x & 63;
    const int g    = lane >> 4;        // 0..3  (k-group / row-group)
    const int c    = lane & 15;        // 0..15 (col within fragment)
    const int gw   = blockIdx.x * 4 + (threadIdx.x >> 6);
    const size_t b0 = (size_t)gw * ROWS;

    // ---- static weight fragments (once per wave, L2-hot) ----
    // W1B[t]:  B-frag of S1: element j = w1_b[m=t*16+g*4+j][r=c]
    // W2BT[t]: A-frag of S2: element j = w2b^T[s=c][n=t*16+g*4+j] = w2_b[n][s]
    // W2A[t]:  B-frag of S3: element j = w2_a[s=g*4+j][k=t*16+c]
    // W1AT[t]: A-frag of S4: element j = w1_a[r=g*4+j][l=t*16+c] * (1/16)
    h4 W1B[4], W2BT[4], W2A[4], W1AT[4];
#pragma unroll
    for (int t = 0; t < 4; ++t) {
        const int kb = t * 16 + g * 4;
        W1B[t]  = pack4(w1_b[(kb+0)*16 + c], w1_b[(kb+1)*16 + c],
                        w1_b[(kb+2)*16 + c], w1_b[(kb+3)*16 + c]);
        W2BT[t] = pack4(w2_b[(kb+0)*16 + c], w2_b[(kb+1)*16 + c],
                        w2_b[(kb+2)*16 + c], w2_b[(kb+3)*16 + c]);
        W2A[t]  = pack4(w2_a[(g*4+0)*64 + t*16 + c], w2_a[(g*4+1)*64 + t*16 + c],
                        w2_a[(g*4+2)*64 + t*16 + c], w2_a[(g*4+3)*64 + t*16 + c]);
        W1AT[t] = pack4(w1_a[(g*4+0)*64 + t*16 + c] * 0.0625f,
                        w1_a[(g*4+1)*64 + t*16 + c] * 0.0625f,
                        w1_a[(g*4+2)*64 + t*16 + c] * 0.0625f,
                        w1_a[(g*4+3)*64 + t*16 + c] * 0.0625f);
    }

    const f4 zero = {0.f, 0.f, 0.f, 0.f};

#pragma unroll 1
    for (int rr = 0; rr < ROWS; ++rr) {
        const float* xp = x + (b0 + rr) * 4096;

        // ---- load Xb^T A-fragments: lane holds x[m=ks*16+g*4+j][n=nt*16+c]
        // 64 independent dword loads (4x64B segments each), all in flight.
        float xf[4][4][4];
#pragma unroll
        for (int nt = 0; nt < 4; ++nt)
#pragma unroll
            for (int ks = 0; ks < 4; ++ks)
#pragma unroll
                for (int j = 0; j < 4; ++j)
                    xf[nt][ks][j] = xp[(ks*16 + g*4 + j)*64 + nt*16 + c];

        h4 XA[4][4];
#pragma unroll
        for (int nt = 0; nt < 4; ++nt)
#pragma unroll
            for (int ks = 0; ks < 4; ++ks)
                XA[nt][ks] = pack4(xf[nt][ks][0], xf[nt][ks][1],
                                   xf[nt][ks][2], xf[nt][ks][3]);

        // ---- S1: PT[nt] (16n x 16r tile) = sum_ks Xb^T-chunk @ w1b-chunk
        f4 PT[4];
#pragma unroll
        for (int nt = 0; nt < 4; ++nt) {
            f4 acc = zero;
#pragma unroll
            for (int ks = 0; ks < 4; ++ks)
                acc = MFMA16(XA[nt][ks], W1B[ks], acc);
            PT[nt] = acc;   // C: lane -> (col r=c, row n=nt*16+g*4+reg)
        }

        // ---- S2: QT = sum_nt w2b^T-chunk @ PT[nt]  (contract n) ----
        h4 PTH[4];
#pragma unroll
        for (int nt = 0; nt < 4; ++nt)
            PTH[nt] = pack4(PT[nt][0], PT[nt][1], PT[nt][2], PT[nt][3]);
        f4 qa = zero;
#pragma unroll
        for (int nt = 0; nt < 4; ++nt)
            qa = MFMA16(W2BT[nt], PTH[nt], qa);
        // QT C: lane -> (col r=c, row s=g*4+reg); as A-frag of S3: Q[r=c][s=g*4+j]
        h4 QTH = pack4(qa[0], qa[1], qa[2], qa[3]);

        // ---- S3: U[kt] (16r x 16k tile) = Q @ w2a-tile (contract s, K=16) ----
        h4 UH[4];
#pragma unroll
        for (int kt = 0; kt < 4; ++kt) {
            f4 u = MFMA16(QTH, W2A[kt], zero);
            // U C: lane -> (col k=kt*16+c, row r=g*4+reg) == B-frag of S4
            UH[kt] = pack4(u[0], u[1], u[2], u[3]);
        }

        // ---- S4: y[lt][kt] = (w1a^T/16)-tile @ U[kt] (contract r, K=16) ----
        float* op = out + (b0 + rr) * 4096 + g * 256 + c;   // (g*4)*64 + c
#pragma unroll
        for (int lt = 0; lt < 4; ++lt) {
#pragma unroll
            for (int kt = 0; kt < 4; ++kt) {
                f4 y = MFMA16(W1AT[lt], UH[kt], zero);
                // C: lane -> (col k=kt*16+c, row l=lt*16+g*4+reg)
#pragma unroll
                for (int reg = 0; reg < 4; ++reg)
                    op[lt*1024 + reg*64 + kt*16] = y[reg];
            }
        }
    }
}

extern "C" void kernel_launch(void* const* d_in, const int* in_sizes, int n_in,
                              void* d_out, int out_size, void* d_ws, size_t ws_size,
                              hipStream_t stream) {
    const float* x    = (const float*)d_in[0];
    const float* w1_a = (const float*)d_in[1];
    const float* w1_b = (const float*)d_in[2];
    const float* w2_a = (const float*)d_in[3];
    const float* w2_b = (const float*)d_in[4];
    float* out = (float*)d_out;

    // 8192 rows / (4 waves * 2 rows/wave) = 1024 blocks
    dim3 grid(1024), block(256);
    hipLaunchKernelGGL(lokr_kernel, grid, block, 0, stream,
                       x, w1_a, w1_b, w2_a, w2_b, out);
}

// Round 9
// 49.002 us; speedup vs baseline: 1.0251x; 1.0251x over previous
//
#include <hip/hip_runtime.h>

// LoKr via layout-chained MFMA (f16 inputs, fp32 accum), zero LDS.
// R9: contraction order n -> m -> r -> s so x enters as the A-operand with
// K along n (contiguous) -> float4 x loads (16/row vs 64 dwords). 2-row
// register pipeline: row1 loads issue before row0 compute.
// Per batch row b, Xb = reshape(x[b], 64m x 64n):
//   D1[m][s] = sum_n  Xb[m][n]   w2b[n][s]   (16 mfma, A=X float4-loaded)
//   D2[r][s] = sum_m  w1b[m][r]  D1[m][s]    ( 4 mfma, A=w1b^T, B=D1)
//   D3[s][l] = sum_r  D2[r][s]   w1a[r][l]/16 (4 mfma, A=D2^T-frag, B=w1a)
//   y [l][k] = sum_s  D3[s][l]   w2a[s][k]   (16 mfma, A=D3^T-frag, B=w2a)
// Junction rule (verified R7): C-frag(row R, col C) == A-frag(M=C, K=R)
// == B-frag(N=C, K=R) of the next mfma -> whole chain stays in registers.

typedef __fp16 h2 __attribute__((ext_vector_type(2)));
typedef __fp16 h4 __attribute__((ext_vector_type(4)));
typedef float  f4 __attribute__((ext_vector_type(4)));

__device__ __forceinline__ h4 pack4(float a, float b, float c, float d) {
    h2 lo = __builtin_amdgcn_cvt_pkrtz(a, b);
    h2 hi = __builtin_amdgcn_cvt_pkrtz(c, d);
    h4 r;
    r[0] = lo[0]; r[1] = lo[1]; r[2] = hi[0]; r[3] = hi[1];
    return r;
}

#define MFMA16(a, b, c) __builtin_amdgcn_mfma_f32_16x16x16f16((a), (b), (c), 0, 0, 0)

__global__ __launch_bounds__(256) void lokr_kernel(
    const float* __restrict__ x,
    const float* __restrict__ w1_a,   // (16, 64) [r][l]
    const float* __restrict__ w1_b,   // (64, 16) [m][r]
    const float* __restrict__ w2_a,   // (16, 64) [s][k]
    const float* __restrict__ w2_b,   // (64, 16) [n][s]
    float* __restrict__ out)
{
    const int lane = threadIdx.x & 63;
    const int g    = lane >> 4;        // 0..3
    const int c    = lane & 15;        // 0..15
    const int gw   = blockIdx.x * 4 + (threadIdx.x >> 6);
    const size_t b0 = (size_t)gw * 2;  // 2 rows per wave

    // ---- static weight fragments (once per wave, L2-hot) ----
    // W2B[nk]:  B-frag S1 (K=n,N=s): j -> w2_b[n=nk*16+g*4+j][s=c]
    // W1BT[mt]: A-frag S2 (M=r,K=m): j -> w1b^T[r=c][m=mt*16+g*4+j]
    // W1A[lt]:  B-frag S3 (K=r,N=l): j -> w1_a[r=g*4+j][l=lt*16+c] * (1/16)
    // W2A[kt]:  B-frag S4 (K=s,N=k): j -> w2_a[s=g*4+j][k=kt*16+c]
    h4 W2B[4], W1BT[4], W1A[4], W2A[4];
#pragma unroll
    for (int t = 0; t < 4; ++t) {
        const int kb = t * 16 + g * 4;
        W2B[t]  = pack4(w2_b[(kb+0)*16 + c], w2_b[(kb+1)*16 + c],
                        w2_b[(kb+2)*16 + c], w2_b[(kb+3)*16 + c]);
        W1BT[t] = pack4(w1_b[(kb+0)*16 + c], w1_b[(kb+1)*16 + c],
                        w1_b[(kb+2)*16 + c], w1_b[(kb+3)*16 + c]);
        W1A[t]  = pack4(w1_a[(g*4+0)*64 + t*16 + c] * 0.0625f,
                        w1_a[(g*4+1)*64 + t*16 + c] * 0.0625f,
                        w1_a[(g*4+2)*64 + t*16 + c] * 0.0625f,
                        w1_a[(g*4+3)*64 + t*16 + c] * 0.0625f);
        W2A[t]  = pack4(w2_a[(g*4+0)*64 + t*16 + c], w2_a[(g*4+1)*64 + t*16 + c],
                        w2_a[(g*4+2)*64 + t*16 + c], w2_a[(g*4+3)*64 + t*16 + c]);
    }

    const f4 zero = {0.f, 0.f, 0.f, 0.f};

    // x A-frag source: lane (g,c) reads float4 at row m=mt*16+c, col n=nk*16+g*4
    const float* xp0 = x + b0 * 4096;
    const float* xp1 = xp0 + 4096;
    const int xoff = c * 64 + g * 4;   // + mt*1024 + nk*16

    // compute+store one row from its 16 A-fragments
    auto compute_store = [&](const h4* XA, float* opb) {
        // S1: D1[mt] (row m, col s) = sum_nk mfma(XA, W2B)
        f4 D1[4];
#pragma unroll
        for (int mt = 0; mt < 4; ++mt) {
            f4 a = zero;
#pragma unroll
            for (int nk = 0; nk < 4; ++nk)
                a = MFMA16(XA[mt * 4 + nk], W2B[nk], a);
            D1[mt] = a;
        }
        // S2: D2 (row r, col s) = sum_mt mfma(W1BT[mt], D1H[mt])
        f4 d2 = zero;
#pragma unroll
        for (int mt = 0; mt < 4; ++mt)
            d2 = MFMA16(W1BT[mt], pack4(D1[mt][0], D1[mt][1], D1[mt][2], D1[mt][3]), d2);
        h4 D2H = pack4(d2[0], d2[1], d2[2], d2[3]);
        // S3: D3[lt] (row s, col l) = mfma(D2H, W1A[lt])
        h4 D3H[4];
#pragma unroll
        for (int lt = 0; lt < 4; ++lt) {
            f4 d3 = MFMA16(D2H, W1A[lt], zero);
            D3H[lt] = pack4(d3[0], d3[1], d3[2], d3[3]);
        }
        // S4: y (row l=lt*16+g*4+reg, col k=kt*16+c) = mfma(D3H[lt], W2A[kt])
        float* op = opb + g * 256 + c;
#pragma unroll
        for (int lt = 0; lt < 4; ++lt) {
#pragma unroll
            for (int kt = 0; kt < 4; ++kt) {
                f4 y = MFMA16(D3H[lt], W2A[kt], zero);
#pragma unroll
                for (int reg = 0; reg < 4; ++reg)
                    op[lt * 1024 + reg * 64 + kt * 16] = y[reg];
            }
        }
    };

    // ---- 2-row register pipeline ----
    f4 xf[16];
    h4 XA[16];

    // row 0 loads: 16 float4, all in flight
#pragma unroll
    for (int mt = 0; mt < 4; ++mt)
#pragma unroll
        for (int nk = 0; nk < 4; ++nk)
            xf[mt * 4 + nk] = *(const f4*)&xp0[mt * 1024 + nk * 16 + xoff];
    // cvt row 0 (waits vmcnt), freeing xf
#pragma unroll
    for (int i = 0; i < 16; ++i)
        XA[i] = pack4(xf[i][0], xf[i][1], xf[i][2], xf[i][3]);
    // row 1 loads issued BEFORE row 0 compute; pin with sched_barrier
#pragma unroll
    for (int mt = 0; mt < 4; ++mt)
#pragma unroll
        for (int nk = 0; nk < 4; ++nk)
            xf[mt * 4 + nk] = *(const f4*)&xp1[mt * 1024 + nk * 16 + xoff];
    __builtin_amdgcn_sched_barrier(0);

    compute_store(XA, out + b0 * 4096);          // hides row-1 latency

#pragma unroll
    for (int i = 0; i < 16; ++i)
        XA[i] = pack4(xf[i][0], xf[i][1], xf[i][2], xf[i][3]);
    compute_store(XA, out + (b0 + 1) * 4096);
}

extern "C" void kernel_launch(void* const* d_in, const int* in_sizes, int n_in,
                              void* d_out, int out_size, void* d_ws, size_t ws_size,
                              hipStream_t stream) {
    const float* x    = (const float*)d_in[0];
    const float* w1_a = (const float*)d_in[1];
    const float* w1_b = (const float*)d_in[2];
    const float* w2_a = (const float*)d_in[3];
    const float* w2_b = (const float*)d_in[4];
    float* out = (float*)d_out;

    // 8192 rows / (4 waves * 2 rows/wave) = 1024 blocks
    dim3 grid(1024), block(256);
    hipLaunchKernelGGL(lokr_kernel, grid, block, 0, stream,
                       x, w1_a, w1_b, w2_a, w2_b, out);
}